// Round 5
// baseline (215.637 us; speedup 1.0000x reference)
//
#include <hip/hip_runtime.h>
#include <stdint.h>

// ---------------------------------------------------------------------------
// Fused RBF histogram:  hist[o,i] = sum_n exp(-||x_n - c_o||^2 / 2) * x[n,i]
// N=524288, IN=64, OUT=128.  fp32 in/out.
//
// R17: break phase lockstep. Corrected cycle budget per 32-row strip/CU:
// HBM 1600cyc (53% used), LDS ~1000 (33%), MFMA ~770 (26%) vs observed
// wall ~3000 ~= SUM of pipes -> phases run serially. The 256-thread
// 4-wave lockstep block keeps every wave in the same phase (stage ->
// compute -> vmcnt(0) drain at barrier), idling each pipe in turn; that's
// why occupancy/barrier/LDS/prefetch sweeps AND R14/R16 were all neutral.
// Fix: 128-thread blocks (2 waves), GRIDN=1024, NITER=16. Wave w owns
// o-tiles 4w..4w+3 for BOTH row-halves of the block's private strip.
//  - 4 independently-drifting blocks/CU -> cross-block pipe overlap.
//  - per-row-of-x LDS reads halve (no 4-wave re-read of the same rows);
//    redundant identity-transpose MFMA halves (2 waves not 4 per strip).
//  - waves own disjoint o -> merge-free epilogue, direct atomics
//    (1024 blocks x 8192; R13 measured atomic path == ws path).
//  - core math unchanged (R8/R11/R16-verified): fp16 MFMA32 scores with
//    c*log2e RNE, C/D==A-frag identity, transpose-MFMA, exp2 +38 bias,
//    RTZ P-pack (absmax 2.9e-11, 3.8x margin).
//  - pipeline structure per block = R14 (verified): 1 barrier/strip,
//    dbuf LDS, 2-deep register prefetch.
// ---------------------------------------------------------------------------

typedef _Float16 half8v __attribute__((ext_vector_type(8)));
typedef _Float16 half4v __attribute__((ext_vector_type(4)));
typedef __fp16  fp16x2 __attribute__((ext_vector_type(2)));
typedef float floatx4 __attribute__((ext_vector_type(4)));

#define GRIDN 1024       // 4 blocks/CU x 256 CUs (128-thread blocks)
#define NITER 16         // 16384 32-row strips / 1024 blocks
#define LOG2E 1.4426950408889634f
#define PBIAS 38.0f                       // P scaled by 2^38 into fp16 range
#define PUNSCALE 3.637978807091713e-12f   // 2^-38 (exact power of two)

#if __has_builtin(__builtin_amdgcn_exp2f)
#define EXP2F(x) __builtin_amdgcn_exp2f(x)
#else
#define EXP2F(x) exp2f(x)
#endif

// pack two fp32 -> fp16x2, RTZ (1 inst v_cvt_pkrtz_f16_f32)
static __device__ __forceinline__ unsigned int pk16z(float a, float b) {
  fp16x2 h = __builtin_amdgcn_cvt_pkrtz(a, b);
  return __builtin_bit_cast(unsigned int, h);
}
// pack two fp32 -> fp16x2, RNE — for x and c (their quantization dominates)
static __device__ __forceinline__ unsigned int pk16(float a, float b) {
  unsigned short ha = __builtin_bit_cast(unsigned short, (_Float16)a);
  unsigned short hb = __builtin_bit_cast(unsigned short, (_Float16)b);
  return (unsigned int)ha | ((unsigned int)hb << 16);
}
static __device__ __forceinline__ half4v mkh4(unsigned int lo, unsigned int hi) {
  uint2 u{lo, hi};
  return __builtin_bit_cast(half4v, u);
}
static __device__ __forceinline__ half8v mkh8(unsigned int a, unsigned int b,
                                              unsigned int c, unsigned int d) {
  uint4 u{a, b, c, d};
  return __builtin_bit_cast(half8v, u);
}

static __device__ __forceinline__ floatx4 mfma32(half8v a, half8v b, floatx4 c) {
  return __builtin_amdgcn_mfma_f32_16x16x32_f16(a, b, c, 0, 0, 0);
}
static __device__ __forceinline__ floatx4 mfma16(half4v a, half4v b, floatx4 c) {
  return __builtin_amdgcn_mfma_f32_16x16x16f16(a, b, c, 0, 0, 0);
}

// sXh row stride 72 shorts = 144 B: 16B-aligned rows, bank step 4 words
// -> <=2-way conflicts on b128/b64 frag reads (free per m136).
#define LSTR 72

__global__ __launch_bounds__(128, 2) void rbf_hist_kernel(
    const float* __restrict__ x, const float* __restrict__ c,
    float* __restrict__ out) {
  __shared__ unsigned short sXh[2][32][LSTR];  // fp16(x) strips, double-buffered
  __shared__ float          sX2[2][32];        // -0.5*log2e*||x_n||^2 (fp32)

  const int t    = threadIdx.x;    // 0..127
  const int lane = t & 63;
  const int w    = t >> 6;         // wave 0..1; owns o-tiles 4w..4w+3
  const int l15  = lane & 15;
  const int quad = lane >> 4;
  const int ob   = w * 4;          // o-tile base

  // ---- one-time: c*log2e fp16 (RNE) fragments for this wave's 4 o-tiles ----
  half8v chi[4][2];
  float m2c[4];                    // -0.5*log2e*||c_o||^2 + PBIAS
#pragma unroll
  for (int oo = 0; oo < 4; ++oo) {
    const int ot = ob + oo;
    float sq = 0.f;
#pragma unroll
    for (int s = 0; s < 2; ++s) {
      const float* p = c + (ot * 16 + l15) * 64 + s * 32 + quad * 8;
      float4 va = *(const float4*)(p);
      float4 vb = *(const float4*)(p + 4);
      float f[8] = {va.x, va.y, va.z, va.w, vb.x, vb.y, vb.z, vb.w};
      unsigned int h[4];
#pragma unroll
      for (int jp = 0; jp < 4; ++jp) {
        float a = f[2 * jp], b = f[2 * jp + 1];
        sq = fmaf(a, a, sq);
        sq = fmaf(b, b, sq);
        h[jp] = pk16(a * LOG2E, b * LOG2E);   // RNE
      }
      chi[oo][s] = mkh8(h[0], h[1], h[2], h[3]);
    }
    sq += __shfl_xor(sq, 16);
    sq += __shfl_xor(sq, 32);
    m2c[oo] = fmaf(-0.5f * LOG2E, sq, PBIAS);
  }

  // identity B-frag for the transpose MFMA: I[k=quad*4+j][col=l15]
  half4v iden;
  {
    float e0 = (quad * 4 + 0 == l15) ? 1.f : 0.f;
    float e1 = (quad * 4 + 1 == l15) ? 1.f : 0.f;
    float e2 = (quad * 4 + 2 == l15) ? 1.f : 0.f;
    float e3 = (quad * 4 + 3 == l15) ? 1.f : 0.f;
    iden = mkh4(pk16z(e0, e1), pk16z(e2, e3));  // exact
  }

  // persistent histogram accumulators: 4 o-tiles x 4 i-tiles (scaled 2^38)
  floatx4 hacc[4][4];
#pragma unroll
  for (int a = 0; a < 4; ++a)
#pragma unroll
    for (int b = 0; b < 4; ++b) {
      floatx4 z = {0.f, 0.f, 0.f, 0.f};
      hacc[a][b] = z;
    }

  // staging map: thread t -> row r=t>>2 (0..31), cols q*16 .. q*16+15 (q=t&3)
  const int r = t >> 2, q = t & 3;

  // convert one strip's registers -> fp16 LDS + exact fp32 x2, buffer B
  auto stage = [&](int B, const float4* v) {
    float f0 = v[0].x, f1 = v[0].y, f2 = v[0].z, f3 = v[0].w;
    float f4 = v[1].x, f5 = v[1].y, f6 = v[1].z, f7 = v[1].w;
    float f8 = v[2].x, f9 = v[2].y, fa = v[2].z, fb = v[2].w;
    float fc = v[3].x, fd = v[3].y, fe = v[3].z, ff = v[3].w;
    float sq = 0.f;
    sq = fmaf(f0, f0, sq); sq = fmaf(f1, f1, sq);
    sq = fmaf(f2, f2, sq); sq = fmaf(f3, f3, sq);
    sq = fmaf(f4, f4, sq); sq = fmaf(f5, f5, sq);
    sq = fmaf(f6, f6, sq); sq = fmaf(f7, f7, sq);
    sq = fmaf(f8, f8, sq); sq = fmaf(f9, f9, sq);
    sq = fmaf(fa, fa, sq); sq = fmaf(fb, fb, sq);
    sq = fmaf(fc, fc, sq); sq = fmaf(fd, fd, sq);
    sq = fmaf(fe, fe, sq); sq = fmaf(ff, ff, sq);
    *(uint4*)&sXh[B][r][q * 16] =
        uint4{pk16(f0, f1), pk16(f2, f3), pk16(f4, f5), pk16(f6, f7)};
    *(uint4*)&sXh[B][r][q * 16 + 8] =
        uint4{pk16(f8, f9), pk16(fa, fb), pk16(fc, fd), pk16(fe, ff)};
    // threads 4r..4r+3 (same wave) share row r
    sq += __shfl_xor(sq, 1);
    sq += __shfl_xor(sq, 2);
    if (q == 0) sX2[B][r] = -0.5f * LOG2E * sq;
  };

  // compute both row-halves of one strip from buffer B into hacc
  auto compute = [&](int B) {
#pragma unroll
    for (int t2 = 0; t2 < 2; ++t2) {
      half8v xh0 = *(const half8v*)&sXh[B][t2 * 16 + l15][quad * 8];
      half8v xh1 = *(const half8v*)&sXh[B][t2 * 16 + l15][32 + quad * 8];
      float4 m2x = *(const float4*)&sX2[B][t2 * 16 + quad * 4];

      // stage A: 2 MFMAs per o-tile (fp16 x * fp16 c, both RNE)
      half4v P[4];
#pragma unroll
      for (int oo = 0; oo < 4; ++oo) {
        floatx4 acc = {m2x.x + m2c[oo], m2x.y + m2c[oo],
                       m2x.z + m2c[oo], m2x.w + m2c[oo]};
        acc = mfma32(xh0, chi[oo][0], acc);
        acc = mfma32(xh1, chi[oo][1], acc);
        // acc == log2e*(-d/2) + 38 ; C-frag == K=16 A-frag (R8-verified)
        P[oo] = mkh4(pk16z(EXP2F(acc[0]), EXP2F(acc[1])),
                     pk16z(EXP2F(acc[2]), EXP2F(acc[3])));  // RTZ, 1 inst
      }

      // transpose x via MFMA identity (R8-verified): b64 row-major reads
      half4v XT[4];
#pragma unroll
      for (int itl = 0; itl < 4; ++itl) {
        half4v ax = *(const half4v*)&sXh[B][t2 * 16 + l15][itl * 16 + quad * 4];
        floatx4 z = {0.f, 0.f, 0.f, 0.f};
        floatx4 d = mfma16(ax, iden, z);
        XT[itl] = mkh4(pk16z(d[0], d[1]), pk16z(d[2], d[3]));  // exact
      }

      // stage B: hist += P * X^T (K=16)
#pragma unroll
      for (int oo = 0; oo < 4; ++oo)
#pragma unroll
        for (int itl = 0; itl < 4; ++itl)
          hacc[oo][itl] = mfma16(P[oo], XT[itl], hacc[oo][itl]);
    }
  };

  // ---- prologue: stage strips 0,1 directly; prefetch strips 2,3 to regs ----
  {
    float4 a[4], b[4];
    const float* p0 = x + ((size_t)blockIdx.x * 32 + r) * 64 + q * 16;
    a[0] = *(const float4*)(p0);
    a[1] = *(const float4*)(p0 + 4);
    a[2] = *(const float4*)(p0 + 8);
    a[3] = *(const float4*)(p0 + 12);
    const float* p1 =
        x + ((size_t)(blockIdx.x + GRIDN) * 32 + r) * 64 + q * 16;
    b[0] = *(const float4*)(p1);
    b[1] = *(const float4*)(p1 + 4);
    b[2] = *(const float4*)(p1 + 8);
    b[3] = *(const float4*)(p1 + 12);
    stage(0, a);
    stage(1, b);
  }
  float4 rA[4], rB[4];   // raw strips it+2 (even) / it+3 (odd)
  {
    const float* pA =
        x + ((size_t)(blockIdx.x + 2 * GRIDN) * 32 + r) * 64 + q * 16;
    rA[0] = *(const float4*)(pA);
    rA[1] = *(const float4*)(pA + 4);
    rA[2] = *(const float4*)(pA + 8);
    rA[3] = *(const float4*)(pA + 12);
    const float* pB =
        x + ((size_t)(blockIdx.x + 3 * GRIDN) * 32 + r) * 64 + q * 16;
    rB[0] = *(const float4*)(pB);
    rB[1] = *(const float4*)(pB + 4);
    rB[2] = *(const float4*)(pB + 8);
    rB[3] = *(const float4*)(pB + 12);
  }
  __syncthreads();

  // ---- main loop: ONE barrier per strip (R14-verified structure) ----
#pragma unroll 1
  for (int it = 0; it < NITER; it += 2) {
    // --- parity 0: strip it ---
    compute(0);
    __syncthreads();
    if (it + 2 < NITER) stage(0, rA);
    if (it + 4 < NITER) {
      const float* p = x +
          ((size_t)(blockIdx.x + (size_t)(it + 4) * GRIDN) * 32 + r) * 64 +
          q * 16;
      rA[0] = *(const float4*)(p);
      rA[1] = *(const float4*)(p + 4);
      rA[2] = *(const float4*)(p + 8);
      rA[3] = *(const float4*)(p + 12);
    }
    // --- parity 1: strip it+1 ---
    compute(1);
    __syncthreads();
    if (it + 3 < NITER) stage(1, rB);
    if (it + 5 < NITER) {
      const float* p = x +
          ((size_t)(blockIdx.x + (size_t)(it + 5) * GRIDN) * 32 + r) * 64 +
          q * 16;
      rB[0] = *(const float4*)(p);
      rB[1] = *(const float4*)(p + 4);
      rB[2] = *(const float4*)(p + 8);
      rB[3] = *(const float4*)(p + 12);
    }
  }

  // ---- epilogue (unscale by 2^-38, exact): direct device-scope atomics ----
  // D: i = itl*16 + l15, o = (ob+oo)*16 + quad*4 + e
  // waves own disjoint o -> 8192 disjoint elements per block, no merge.
#pragma unroll
  for (int oo = 0; oo < 4; ++oo)
#pragma unroll
    for (int itl = 0; itl < 4; ++itl)
#pragma unroll
      for (int e = 0; e < 4; ++e) {
        int o = (ob + oo) * 16 + quad * 4 + e;
        int i = itl * 16 + l15;
        atomicAdd(out + o * 64 + i, hacc[oo][itl][e] * PUNSCALE);
      }
}

__global__ void zero_out_kernel(float* out, int n) {
  int i = blockIdx.x * 256 + threadIdx.x;
  if (i < n) out[i] = 0.f;
}

extern "C" void kernel_launch(void* const* d_in, const int* in_sizes, int n_in,
                              void* d_out, int out_size, void* d_ws, size_t ws_size,
                              hipStream_t stream) {
  (void)in_sizes; (void)n_in; (void)d_ws; (void)ws_size;
  const float* x = (const float*)d_in[0];        // [524288, 64]
  const float* c = (const float*)d_in[1];        // [128, 64]
  float* out = (float*)d_out;                    // [128, 64]

  zero_out_kernel<<<(out_size + 255) / 256, 256, 0, stream>>>(out, out_size);
  rbf_hist_kernel<<<GRIDN, 128, 0, stream>>>(x, c, out);
}

// Round 6
// 195.025 us; speedup vs baseline: 1.1057x; 1.1057x over previous
//
#include <hip/hip_runtime.h>
#include <stdint.h>

// ---------------------------------------------------------------------------
// Fused RBF histogram:  hist[o,i] = sum_n exp(-||x_n - c_o||^2 / 2) * x[n,i]
// N=524288, IN=64, OUT=128.  fp32 in/out.
//
// R18: revert to the verified R13/R12 core (198.06us) + store-based reduce.
// Theory ledger: ws-poison(R13), barriers(R14), tr-read(R15), LDS-BW(R16),
// phase-lockstep(R17) all falsified; prior session swept 7 more axes —
// hist is pinned ~41.5us vs 21.3us x-read floor, and ~155us of dur is the
// harness's unconditional 2x512MiB ws-poison fills. R17's profile showed
// the atomic epilogue writes through to HBM (4B/atomic, 32MB at 1024
// blocks), so: back to 512 blocks, ws-streaming partials (measured == 
// atomic path, and the poison is paid regardless), and a reduce that
// combines 8x64-partial sums in a fixed LDS tree with PLAIN stores —
// eliminating zero_out (one dispatch, ~1.5-2us) and all output atomics.
//  - hist core byte-identical to R13 (R8/R11-verified math: fp16 MFMA32
//    scores with c*log2e RNE, C/D==A-frag identity, transpose-MFMA,
//    exp2 +38 bias, RTZ P-pack; absmax 2.9e-11, 3.8x margin).
//  - atomic fallback (with zero_out) kept for small-ws harnesses.
// ---------------------------------------------------------------------------

typedef _Float16 half8v __attribute__((ext_vector_type(8)));
typedef _Float16 half4v __attribute__((ext_vector_type(4)));
typedef __fp16  fp16x2 __attribute__((ext_vector_type(2)));
typedef float floatx4 __attribute__((ext_vector_type(4)));

#define GRIDN 512        // 2 blocks/CU x 256 CUs
#define NITER 32         // 16384 32-row strips / 512 blocks
#define LOG2E 1.4426950408889634f
#define PBIAS 38.0f                       // P scaled by 2^38 into fp16 range
#define PUNSCALE 3.637978807091713e-12f   // 2^-38 (exact power of two)

#if __has_builtin(__builtin_amdgcn_exp2f)
#define EXP2F(x) __builtin_amdgcn_exp2f(x)
#else
#define EXP2F(x) exp2f(x)
#endif

// pack two fp32 -> fp16x2, RTZ (1 inst v_cvt_pkrtz_f16_f32)
static __device__ __forceinline__ unsigned int pk16z(float a, float b) {
  fp16x2 h = __builtin_amdgcn_cvt_pkrtz(a, b);
  return __builtin_bit_cast(unsigned int, h);
}
// pack two fp32 -> fp16x2, RNE — for x and c (their quantization dominates)
static __device__ __forceinline__ unsigned int pk16(float a, float b) {
  unsigned short ha = __builtin_bit_cast(unsigned short, (_Float16)a);
  unsigned short hb = __builtin_bit_cast(unsigned short, (_Float16)b);
  return (unsigned int)ha | ((unsigned int)hb << 16);
}
static __device__ __forceinline__ half4v mkh4(unsigned int lo, unsigned int hi) {
  uint2 u{lo, hi};
  return __builtin_bit_cast(half4v, u);
}
static __device__ __forceinline__ half8v mkh8(unsigned int a, unsigned int b,
                                              unsigned int c, unsigned int d) {
  uint4 u{a, b, c, d};
  return __builtin_bit_cast(half8v, u);
}

static __device__ __forceinline__ floatx4 mfma32(half8v a, half8v b, floatx4 c) {
  return __builtin_amdgcn_mfma_f32_16x16x32_f16(a, b, c, 0, 0, 0);
}
static __device__ __forceinline__ floatx4 mfma16(half4v a, half4v b, floatx4 c) {
  return __builtin_amdgcn_mfma_f32_16x16x16f16(a, b, c, 0, 0, 0);
}

// sXh row stride 72 shorts = 144 B: 16B-aligned rows, bank step 4 words
// -> <=2-way conflicts on b128/b64 frag reads (free per m136).
#define LSTR 72

__global__ __launch_bounds__(256, 4) void rbf_hist_kernel(
    const float* __restrict__ x, const float* __restrict__ c,
    float* __restrict__ out, float* __restrict__ ws, int use_ws) {
  __shared__ unsigned short sXh[32][LSTR];  // fp16(x) strip, row-major [n][i]
  __shared__ float          sX2[32];        // -0.5*log2e*||x_n||^2 (fp32 exact)

  const int t    = threadIdx.x;    // 0..255
  const int lane = t & 63;
  const int w    = t >> 6;         // wave 0..3; owns o-tiles {2w, 2w+1}
  const int l15  = lane & 15;
  const int quad = lane >> 4;

  // ---- one-time: c*log2e fp16 (RNE) fragments for this wave's 2 o-tiles ----
  half8v chi[2][2];
  float m2c[2];                    // -0.5*log2e*||c_o||^2 + PBIAS
#pragma unroll
  for (int oo = 0; oo < 2; ++oo) {
    const int ot = 2 * w + oo;
    float sq = 0.f;
#pragma unroll
    for (int s = 0; s < 2; ++s) {
      const float* p = c + (ot * 16 + l15) * 64 + s * 32 + quad * 8;
      float4 va = *(const float4*)(p);
      float4 vb = *(const float4*)(p + 4);
      float f[8] = {va.x, va.y, va.z, va.w, vb.x, vb.y, vb.z, vb.w};
      unsigned int h[4];
#pragma unroll
      for (int jp = 0; jp < 4; ++jp) {
        float a = f[2 * jp], b = f[2 * jp + 1];
        sq = fmaf(a, a, sq);
        sq = fmaf(b, b, sq);
        h[jp] = pk16(a * LOG2E, b * LOG2E);   // RNE
      }
      chi[oo][s] = mkh8(h[0], h[1], h[2], h[3]);
    }
    sq += __shfl_xor(sq, 16);
    sq += __shfl_xor(sq, 32);
    m2c[oo] = fmaf(-0.5f * LOG2E, sq, PBIAS);
  }

  // identity B-frag for the transpose MFMA: I[k=quad*4+j][col=l15]
  half4v iden;
  {
    float e0 = (quad * 4 + 0 == l15) ? 1.f : 0.f;
    float e1 = (quad * 4 + 1 == l15) ? 1.f : 0.f;
    float e2 = (quad * 4 + 2 == l15) ? 1.f : 0.f;
    float e3 = (quad * 4 + 3 == l15) ? 1.f : 0.f;
    iden = mkh4(pk16z(e0, e1), pk16z(e2, e3));  // exact
  }

  // persistent histogram accumulators: 2 o-tiles x 4 i-tiles (scaled 2^38)
  floatx4 hacc[2][4];
#pragma unroll
  for (int a = 0; a < 2; ++a)
#pragma unroll
    for (int b = 0; b < 4; ++b) {
      floatx4 z = {0.f, 0.f, 0.f, 0.f};
      hacc[a][b] = z;
    }

  // staging map: thread t -> row r=t>>3 (0..31), cols q*8 .. q*8+7 (q=t&7)
  const int r = t >> 3, q = t & 7;

  // 2-deep prefetch ring: vA holds even strips, vB odd strips.
  float4 vA[2], vB[2];
  {
    const float* pA = x + ((size_t)blockIdx.x * 32 + r) * 64 + q * 8;
    vA[0] = *(const float4*)(pA);
    vA[1] = *(const float4*)(pA + 4);
    const float* pB =
        x + ((size_t)(blockIdx.x + GRIDN) * 32 + r) * 64 + q * 8;
    vB[0] = *(const float4*)(pB);
    vB[1] = *(const float4*)(pB + 4);
  }

#pragma unroll 1
  for (int it = 0; it < NITER; it += 2) {
#pragma unroll
    for (int par = 0; par < 2; ++par) {
      float4* v = (par == 0) ? vA : vB;

      __syncthreads();  // prev strip's sXh reads done -> safe to overwrite

      // ---- staging: fp16 RNE convert -> LDS row-major + exact fp32 x2 ----
      {
        float f0 = v[0].x, f1 = v[0].y, f2 = v[0].z, f3 = v[0].w;
        float f4 = v[1].x, f5 = v[1].y, f6 = v[1].z, f7 = v[1].w;
        float sq = 0.f;
        sq = fmaf(f0, f0, sq); sq = fmaf(f1, f1, sq);
        sq = fmaf(f2, f2, sq); sq = fmaf(f3, f3, sq);
        sq = fmaf(f4, f4, sq); sq = fmaf(f5, f5, sq);
        sq = fmaf(f6, f6, sq); sq = fmaf(f7, f7, sq);
        *(uint4*)&sXh[r][q * 8] =
            uint4{pk16(f0, f1), pk16(f2, f3), pk16(f4, f5), pk16(f6, f7)};
        // threads 8r..8r+7 (same wave) share row r
        sq += __shfl_xor(sq, 1);
        sq += __shfl_xor(sq, 2);
        sq += __shfl_xor(sq, 4);
        if (q == 0) sX2[r] = -0.5f * LOG2E * sq;
      }
      __syncthreads();  // strip ready

      // prefetch strip it+par+2 into this parity's buffer (issued after the
      // barrier — R5 lesson; lands during ~2 compute phases)
      if (it + par + 2 < NITER) {
        const float* p = x +
            ((size_t)(blockIdx.x + (it + par + 2) * GRIDN) * 32 + r) * 64 +
            q * 8;
        v[0] = *(const float4*)(p);
        v[1] = *(const float4*)(p + 4);
      }

      // ---- per 16-row sub-tile: scores -> exp2 -> P -> transpose -> hist ----
#pragma unroll
      for (int t2 = 0; t2 < 2; ++t2) {
        half8v xh0 = *(const half8v*)&sXh[t2 * 16 + l15][quad * 8];
        half8v xh1 = *(const half8v*)&sXh[t2 * 16 + l15][32 + quad * 8];
        float4 m2x = *(const float4*)&sX2[t2 * 16 + quad * 4];

        // stage A: 2 MFMAs per o-tile (fp16 x * fp16 c, both RNE)
        half4v P[2];
#pragma unroll
        for (int oo = 0; oo < 2; ++oo) {
          floatx4 acc = {m2x.x + m2c[oo], m2x.y + m2c[oo],
                         m2x.z + m2c[oo], m2x.w + m2c[oo]};
          acc = mfma32(xh0, chi[oo][0], acc);
          acc = mfma32(xh1, chi[oo][1], acc);
          // acc == log2e*(-d/2) + 38 ; C-frag == K=16 A-frag (R8-verified)
          P[oo] = mkh4(pk16z(EXP2F(acc[0]), EXP2F(acc[1])),
                       pk16z(EXP2F(acc[2]), EXP2F(acc[3])));  // RTZ, 1 inst
        }

        // transpose x via MFMA identity (R8-verified): b64 row-major reads
        half4v XT[4];
#pragma unroll
        for (int itl = 0; itl < 4; ++itl) {
          half4v ax = *(const half4v*)&sXh[t2 * 16 + l15][itl * 16 + quad * 4];
          floatx4 z = {0.f, 0.f, 0.f, 0.f};
          floatx4 d = mfma16(ax, iden, z);
          XT[itl] = mkh4(pk16z(d[0], d[1]), pk16z(d[2], d[3]));  // exact
        }

        // stage B: hist += P * X^T (K=16)
#pragma unroll
        for (int oo = 0; oo < 2; ++oo)
#pragma unroll
          for (int itl = 0; itl < 4; ++itl)
            hacc[oo][itl] = mfma16(P[oo], XT[itl], hacc[oo][itl]);
      }
    }
  }

  // ---- epilogue (unscale by 2^-38, exact) ----
  // D: i = itl*16 + l15, o = (2w+oo)*16 + quad*4 + e
  if (use_ws) {
    float* part = ws + (size_t)blockIdx.x * 8192;
#pragma unroll
    for (int oo = 0; oo < 2; ++oo)
#pragma unroll
      for (int itl = 0; itl < 4; ++itl)
#pragma unroll
        for (int e = 0; e < 4; ++e) {
          int o = (2 * w + oo) * 16 + quad * 4 + e;
          int i = itl * 16 + l15;
          part[o * 64 + i] = hacc[oo][itl][e] * PUNSCALE;
        }
  } else {
#pragma unroll
    for (int oo = 0; oo < 2; ++oo)
#pragma unroll
      for (int itl = 0; itl < 4; ++itl)
#pragma unroll
        for (int e = 0; e < 4; ++e) {
          int o = (2 * w + oo) * 16 + quad * 4 + e;
          int i = itl * 16 + l15;
          atomicAdd(out + o * 64 + i, hacc[oo][itl][e] * PUNSCALE);
        }
  }
}

// sum 512 per-block partials -> out, NO atomics, NO pre-zero.
// 256 blocks x 256 threads; block b owns elems e in [b*32, b*32+32).
// thread (pp=tid>>5, le=tid&31): partial sum of 64 blocks pp*64..pp*64+63,
// combined in a fixed LDS tree -> one plain store per element.
__global__ __launch_bounds__(256) void reduce_kernel(
    const float* __restrict__ ws, float* __restrict__ out) {
  __shared__ float sP[8][32];
  const int le = threadIdx.x & 31;
  const int pp = threadIdx.x >> 5;              // 0..7
  const int e  = blockIdx.x * 32 + le;          // 0..8191
  const float* p = ws + (size_t)(pp * 64) * 8192 + e;
  float s = 0.f;
#pragma unroll 8
  for (int k = 0; k < 64; ++k) s += p[(size_t)k * 8192];
  sP[pp][le] = s;
  __syncthreads();
  if (pp == 0) {
    float r = ((sP[0][le] + sP[1][le]) + (sP[2][le] + sP[3][le])) +
              ((sP[4][le] + sP[5][le]) + (sP[6][le] + sP[7][le]));
    out[e] = r;
  }
}

__global__ void zero_out_kernel(float* out, int n) {
  int i = blockIdx.x * 256 + threadIdx.x;
  if (i < n) out[i] = 0.f;
}

extern "C" void kernel_launch(void* const* d_in, const int* in_sizes, int n_in,
                              void* d_out, int out_size, void* d_ws, size_t ws_size,
                              hipStream_t stream) {
  (void)in_sizes; (void)n_in;
  const float* x = (const float*)d_in[0];        // [524288, 64]
  const float* c = (const float*)d_in[1];        // [128, 64]
  float* out = (float*)d_out;                    // [128, 64]
  float* ws  = (float*)d_ws;

  const int use_ws = (ws_size >= (size_t)GRIDN * 8192 * sizeof(float)) ? 1 : 0;

  if (use_ws) {
    rbf_hist_kernel<<<GRIDN, 256, 0, stream>>>(x, c, out, ws, 1);
    reduce_kernel<<<256, 256, 0, stream>>>(ws, out);
  } else {
    zero_out_kernel<<<(out_size + 255) / 256, 256, 0, stream>>>(out, out_size);
    rbf_hist_kernel<<<GRIDN, 256, 0, stream>>>(x, c, out, ws, 0);
  }
}